// Round 16
// baseline (631.530 us; speedup 1.0000x reference)
//
#include <hip/hip_runtime.h>
#include <stdint.h>

// Problem constants
constexpr int SEQ   = 2048;
constexpr int NHEAD = 16;
constexpr int HDSZ  = 128;   // head dim
constexpr int HDIM  = 2048;  // model dim
constexpr float QK_SCALE = 0.08838834764831845f; // 1/sqrt(128)

typedef __attribute__((ext_vector_type(8))) __bf16 bf16x8;
typedef __attribute__((ext_vector_type(4))) __bf16 bf16x4;
typedef __attribute__((ext_vector_type(2))) __bf16 bf16x2;
typedef __attribute__((ext_vector_type(4))) float  f32x4;

__device__ __forceinline__ void gl_lds16(const void* gptr, void* lptr) {
  // async global->LDS, 16B/lane; LDS dst is wave-uniform base + lane*16
  __builtin_amdgcn_global_load_lds(
      (const __attribute__((address_space(1))) unsigned int*)gptr,
      (__attribute__((address_space(3))) unsigned int*)lptr, 16, 0, 0);
}

// ---------------- merged fp32 -> bf16 cast (x + 4 weights, one launch) -------
__global__ __launch_bounds__(256) void cast6_f32_bf16(
    const float* __restrict__ x,  const float* __restrict__ w0,
    const float* __restrict__ w1, const float* __restrict__ w2,
    const float* __restrict__ w3, __bf16* __restrict__ out, int n4) {
  const int y = blockIdx.y;
  const float* src =
      (y == 0) ? x : (y == 1) ? x + (size_t)n4 * 4
      : (y == 2) ? w0 : (y == 3) ? w1 : (y == 4) ? w2 : w3;
  __bf16* dst = out + (size_t)y * (size_t)n4 * 4;
  int i = blockIdx.x * blockDim.x + threadIdx.x;
  int stride = gridDim.x * blockDim.x;
  for (; i < n4; i += stride) {
    float4 v = ((const float4*)src)[i];
    bf16x4 o = { (__bf16)v.x, (__bf16)v.y, (__bf16)v.z, (__bf16)v.w };
    ((bf16x4*)dst)[i] = o;
  }
}

// ---------------- merged QKV GEMM (BK=64, T2 swizzle, static dbuf) -----------
// (unchanged from R13/R15)
__global__ __launch_bounds__(256) void gemm_qkv(
    const __bf16* __restrict__ A, const __bf16* __restrict__ W,
    __bf16* __restrict__ qkv) {
  constexpr long XN = 4096L * 2048;
  constexpr int K = 2048;
  __shared__ __align__(16) char smem[4 * 16384];  // As0|Bs0|As1|Bs1
  __bf16* const As0 = (__bf16*)(smem);
  __bf16* const Bs0 = (__bf16*)(smem + 16384);
  __bf16* const As1 = (__bf16*)(smem + 32768);
  __bf16* const Bs1 = (__bf16*)(smem + 49152);
  __bf16* const Ts  = (__bf16*)(smem);            // [64][136] epilogue reuse

  const int tid  = threadIdx.x;
  const int lane = tid & 63;
  const int w    = tid >> 6;
  const int lg   = lane >> 4, lr = lane & 15;
  const int wr   = w >> 1, wc = w & 1;
  const int flat = blockIdx.y * 48 + blockIdx.x;
  const int x8 = flat & 7, k = flat >> 3;        // k in 0..191
  const int xm = x8 & 3, xn = x8 >> 2;
  const int mtile = xm * 8 + (k & 7);
  const int ntile = xn * 24 + (k >> 3);
  const long mbase = (long)mtile * 128;
  const long nbase = (long)ntile * 128;

  f32x4 acc[4][4];
#pragma unroll
  for (int i = 0; i < 4; ++i)
#pragma unroll
    for (int j = 0; j < 4; ++j) acc[i][j] = (f32x4){0.f, 0.f, 0.f, 0.f};

  const __bf16* asrc[4];
  const __bf16* wsrc[4];
#pragma unroll
  for (int i = 0; i < 4; ++i) {
    const int row = w * 32 + i * 8 + (lane >> 3);
    const int cs  = ((lane & 7) ^ (row & 7)) * 8;
    asrc[i] = A + (mbase + row) * (long)K + cs;
    wsrc[i] = W + (nbase + row) * (long)K + cs;
  }

  auto stageto = [&](__bf16* As, __bf16* Bs, int ko) {
#pragma unroll
    for (int i = 0; i < 4; ++i) {
      gl_lds16(asrc[i] + ko, &As[(w * 32 + i * 8) * 64]);
      gl_lds16(wsrc[i] + ko, &Bs[(w * 32 + i * 8) * 64]);
    }
  };
  auto computeb = [&](const __bf16* As, const __bf16* Bs) {
#pragma unroll
    for (int kk = 0; kk < 2; ++kk) {
      const int cp = ((kk * 4 + lg) ^ (lr & 7)) << 4;
      bf16x8 af[4], bfv[4];
#pragma unroll
      for (int mm = 0; mm < 4; ++mm)
        af[mm] = *(const bf16x8*)(
            (const char*)As + (wr * 64 + mm * 16 + lr) * 128 + cp);
#pragma unroll
      for (int nn = 0; nn < 4; ++nn)
        bfv[nn] = *(const bf16x8*)(
            (const char*)Bs + (wc * 64 + nn * 16 + lr) * 128 + cp);
      __builtin_amdgcn_s_setprio(1);
#pragma unroll
      for (int nn = 0; nn < 4; ++nn)
#pragma unroll
        for (int mm = 0; mm < 4; ++mm)
          acc[mm][nn] = __builtin_amdgcn_mfma_f32_16x16x32_bf16(
              af[mm], bfv[nn], acc[mm][nn], 0, 0, 0);
      __builtin_amdgcn_s_setprio(0);
    }
  };

  stageto(As0, Bs0, 0);
  __syncthreads();

  int ko = 64;
  for (int tp = 0; tp < 15; ++tp) {
    stageto(As1, Bs1, ko);
    __builtin_amdgcn_sched_barrier(0);
    computeb(As0, Bs0);
    __syncthreads();
    stageto(As0, Bs0, ko + 64);
    __builtin_amdgcn_sched_barrier(0);
    computeb(As1, Bs1);
    __syncthreads();
    ko += 128;
  }
  stageto(As1, Bs1, ko);
  __builtin_amdgcn_sched_barrier(0);
  computeb(As0, Bs0);
  __syncthreads();
  computeb(As1, Bs1);
  __syncthreads();  // before Ts reuse

  const int  mat = ntile >> 4;                // 0=Q, 1=K, 2=V
  const long nb2 = nbase - (long)mat * 2048;
  const long b   = mbase >> 11, s0 = mbase & 2047;
  const long h   = nb2 >> 7;

  if (mat < 2) {
    __bf16* out = qkv + (size_t)mat * XN;
#pragma unroll
    for (int dh = 0; dh < 2; ++dh) {
      if (wr == dh) {
#pragma unroll
        for (int mm = 0; mm < 4; ++mm)
#pragma unroll
          for (int nn = 0; nn < 4; ++nn) {
            const int d = wc * 64 + nn * 16 + lr;
#pragma unroll
            for (int r = 0; r < 4; ++r)
              Ts[(mm * 16 + lg * 4 + r) * 136 + d] = (__bf16)acc[mm][nn][r];
          }
      }
      __syncthreads();
#pragma unroll
      for (int it = 0; it < 4; ++it) {
        const int idx = it * 256 + tid;
        const int row = idx >> 4, c = idx & 15;
        bf16x8 v = *(const bf16x8*)&Ts[row * 136 + c * 8];
        *(bf16x8*)&out[((b * NHEAD + h) * SEQ + s0 + dh * 64 + row) * HDSZ +
                       c * 8] = v;
      }
      __syncthreads();
    }
  } else {
    __bf16* out = qkv + 2 * XN;
#pragma unroll
    for (int dh = 0; dh < 2; ++dh) {
      if (wc == dh) {
#pragma unroll
        for (int mm = 0; mm < 4; ++mm)
#pragma unroll
          for (int nn = 0; nn < 4; ++nn) {
            const int dd = nn * 16 + lr;
            bf16x4 pk = { (__bf16)acc[mm][nn][0], (__bf16)acc[mm][nn][1],
                          (__bf16)acc[mm][nn][2], (__bf16)acc[mm][nn][3] };
            *(bf16x4*)&Ts[dd * 136 + wr * 64 + mm * 16 + lg * 4] = pk;
          }
      }
      __syncthreads();
#pragma unroll
      for (int it = 0; it < 4; ++it) {
        const int idx = it * 256 + tid;
        const int dd = idx >> 4, c = idx & 15;
        bf16x8 v = *(const bf16x8*)&Ts[dd * 136 + c * 8];
        *(bf16x8*)&out[((b * NHEAD + h) * HDSZ + dh * 64 + dd) * SEQ +
                       s0 + c * 8] = v;
      }
      __syncthreads();
    }
  }
}

// ---------------- O-projection GEMM (unchanged from R13/R15) -----------------
__global__ __launch_bounds__(256) void gemm_bt_f32(
    const __bf16* __restrict__ A, const __bf16* __restrict__ B,
    float* __restrict__ C, int M, int N, int K) {
  __shared__ __align__(16) char smem[4 * 16384];
  __bf16* const As0 = (__bf16*)(smem);
  __bf16* const Bs0 = (__bf16*)(smem + 16384);
  __bf16* const As1 = (__bf16*)(smem + 32768);
  __bf16* const Bs1 = (__bf16*)(smem + 49152);

  const int tid  = threadIdx.x;
  const int lane = tid & 63;
  const int w    = tid >> 6;
  const int lg   = lane >> 4, lr = lane & 15;
  const int wr   = w >> 1, wc = w & 1;
  const int flat = blockIdx.y * 16 + blockIdx.x;
  const int x8 = flat & 7, k = flat >> 3;
  const int xm = x8 & 3, xn = x8 >> 2;
  const long mbase = (long)(xm * 8 + (k & 7)) * 128;
  const long nbase = (long)(xn * 8 + (k >> 3)) * 128;

  f32x4 acc[4][4];
#pragma unroll
  for (int i = 0; i < 4; ++i)
#pragma unroll
    for (int j = 0; j < 4; ++j) acc[i][j] = (f32x4){0.f, 0.f, 0.f, 0.f};

  const __bf16* asrc[4];
  const __bf16* bsrc[4];
#pragma unroll
  for (int i = 0; i < 4; ++i) {
    const int row = w * 32 + i * 8 + (lane >> 3);
    const int cs  = ((lane & 7) ^ (row & 7)) * 8;
    asrc[i] = A + (mbase + row) * (long)K + cs;
    bsrc[i] = B + (nbase + row) * (long)K + cs;
  }

  auto stageto = [&](__bf16* As, __bf16* Bs, int ko) {
#pragma unroll
    for (int i = 0; i < 4; ++i) {
      gl_lds16(asrc[i] + ko, &As[(w * 32 + i * 8) * 64]);
      gl_lds16(bsrc[i] + ko, &Bs[(w * 32 + i * 8) * 64]);
    }
  };
  auto computeb = [&](const __bf16* As, const __bf16* Bs) {
#pragma unroll
    for (int kk = 0; kk < 2; ++kk) {
      const int cp = ((kk * 4 + lg) ^ (lr & 7)) << 4;
      bf16x8 af[4], bfv[4];
#pragma unroll
      for (int mm = 0; mm < 4; ++mm)
        af[mm] = *(const bf16x8*)(
            (const char*)As + (wr * 64 + mm * 16 + lr) * 128 + cp);
#pragma unroll
      for (int nn = 0; nn < 4; ++nn)
        bfv[nn] = *(const bf16x8*)(
            (const char*)Bs + (wc * 64 + nn * 16 + lr) * 128 + cp);
      __builtin_amdgcn_s_setprio(1);
#pragma unroll
      for (int nn = 0; nn < 4; ++nn)
#pragma unroll
        for (int mm = 0; mm < 4; ++mm)
          acc[mm][nn] = __builtin_amdgcn_mfma_f32_16x16x32_bf16(
              af[mm], bfv[nn], acc[mm][nn], 0, 0, 0);
      __builtin_amdgcn_s_setprio(0);
    }
  };

  stageto(As0, Bs0, 0);
  __syncthreads();

  int ko = 64;
  for (int tp = 0; tp < 15; ++tp) {
    stageto(As1, Bs1, ko);
    __builtin_amdgcn_sched_barrier(0);
    computeb(As0, Bs0);
    __syncthreads();
    stageto(As0, Bs0, ko + 64);
    __builtin_amdgcn_sched_barrier(0);
    computeb(As1, Bs1);
    __syncthreads();
    ko += 128;
  }
  stageto(As1, Bs1, ko);
  __builtin_amdgcn_sched_barrier(0);
  computeb(As0, Bs0);
  __syncthreads();
  computeb(As1, Bs1);

#pragma unroll
  for (int mm = 0; mm < 4; ++mm)
#pragma unroll
    for (int nn = 0; nn < 4; ++nn) {
      const long n = nbase + wc * 64 + nn * 16 + lr;
#pragma unroll
      for (int r = 0; r < 4; ++r) {
        const long m = mbase + wr * 64 + mm * 16 + lg * 4 + r;
        C[m * (long)N + n] = acc[mm][nn][r];
      }
    }
}

// ---------------- fused flash attention v9: k-split across wave pairs --------
// QBLK=128, KVBLK=64, 8 waves. Wave w: q-rows [(w&3)*32, +32) (rt=0,1),
// k-half kh=w>>2 (32 of 64 k). Each wave reads HALF of K and V (18 b128 vs 34)
// for the same 32 MFMA -> DS-pipe time -28%. The two k-halves run independent
// online softmax (zero per-iter cross-wave sync); exact two-way flash merge at
// the epilogue through the dead K/V LDS. Defer-max (T13) kept per wave.
__global__ __launch_bounds__(512, 4) void attn_fused(
    const __bf16* __restrict__ Q, const __bf16* __restrict__ K,
    const __bf16* __restrict__ Vt, const float* __restrict__ mask,
    __bf16* __restrict__ Out) {
  __shared__ __align__(16) char sm[81920];
  __bf16* const Ks = (__bf16*)sm;             // [2][64][128] swizzled chunks
  __bf16* const Vs = (__bf16*)(sm + 32768);   // [2][128][64] swizzled chunks
  char*   const Pb = sm + 65536;              // per-wave P: 8 x [32][64B]

  const int tid  = threadIdx.x;
  const int lane = tid & 63;
  const int w    = tid >> 6;            // 0..7
  const int lg   = lane >> 4, lr = lane & 15;
  const int qw   = w & 3;               // q-group (32 rows)
  const int kh   = w >> 2;              // k-half (32 cols)
  const int flat = blockIdx.y * 16 + blockIdx.x;
  const int swz  = (flat & 7) * 64 + (flat >> 3);
  const int bh   = swz >> 4;
  const int b    = bh >> 4, h = bh & 15;
  const int q0   = (swz & 15) * 128;

  const __bf16* Qh = Q  + (size_t)bh * SEQ * HDSZ;
  const __bf16* Kh = K  + (size_t)bh * SEQ * HDSZ;
  const __bf16* Vh = Vt + (size_t)bh * HDSZ * SEQ;  // [d][s]
  const float*  Mb = mask + (size_t)b * SEQ * SEQ;

  const int qb = q0 + qw * 32;
  // Q fragments (B-operand: col=lr -> q-row, k=lg*8+i -> d); rt in {0,1}
  bf16x8 qf[2][4];
#pragma unroll
  for (int rt = 0; rt < 2; ++rt)
#pragma unroll
    for (int kk = 0; kk < 4; ++kk)
      qf[rt][kk] = *(const bf16x8*)(
          Qh + (size_t)(qb + rt * 16 + lr) * HDSZ + kk * 32 + lg * 8);

  // staging sources (pre-swizzled global addr, linear LDS dest) — all 8 waves
  const __bf16* ksrc[2];
  const __bf16* vsrc[2];
#pragma unroll
  for (int i = 0; i < 2; ++i) {
    const int ch = i * 512 + tid;
    const int krow = ch >> 4, kc = ch & 15;
    ksrc[i] = Kh + (size_t)krow * HDSZ + (((kc & 8) | ((kc ^ krow) & 7)) * 8);
    const int vrow = ch >> 3, vc = ch & 7;
    vsrc[i] = Vh + (size_t)vrow * SEQ + (((vc ^ vrow) & 7) * 8);
  }

  float mrw[2] = {-1e30f, -1e30f}, lrw[2] = {0.f, 0.f};  // per rt, q = lr
  f32x4 acco[2][8];
#pragma unroll
  for (int rt = 0; rt < 2; ++rt)
#pragma unroll
    for (int n = 0; n < 8; ++n) acco[rt][n] = (f32x4){0.f, 0.f, 0.f, 0.f};

  // prologue: stage tile 0 into buffer 0
#pragma unroll
  for (int i = 0; i < 2; ++i) {
    gl_lds16(ksrc[i], &Ks[(i * 512 + w * 64) * 8]);
    gl_lds16(vsrc[i], &Vs[(i * 512 + w * 64) * 8]);
  }
  __syncthreads();

  char* const Pw = Pb + w * 2048;   // this wave's P: 32 rows x 64 B

  constexpr int NT = SEQ / 64;
  for (int t = 0; t < NT; ++t) {
    const int cur = t & 1;
    const int kt = t * 64;
    const char* Kb = (const char*)(Ks + cur * (64 * 128));
    const char* Vb = (const char*)(Vs + cur * (128 * 64));

    // --- (A) mask prefetch FIRST (oldest vmem); this wave's k-half ---
    f32x4 mk[2][2];
#pragma unroll
    for (int rt = 0; rt < 2; ++rt)
#pragma unroll
      for (int n = 0; n < 2; ++n)
        mk[rt][n] = *(const f32x4*)(
            Mb + (size_t)(qb + rt * 16 + lr) * SEQ + kt + kh * 32 +
            n * 16 + lg * 4);
    __builtin_amdgcn_sched_barrier(0);

    // --- (B) STAGE tile t+1 into buf^1 (drained at end barrier) ---
    if (t + 1 < NT) {
      const int nk = kt + 64;
      __bf16* Kn = Ks + (cur ^ 1) * (64 * 128);
      __bf16* Vn = Vs + (cur ^ 1) * (128 * 64);
#pragma unroll
      for (int i = 0; i < 2; ++i) {
        gl_lds16(ksrc[i] + (size_t)nk * HDSZ, &Kn[(i * 512 + w * 64) * 8]);
        gl_lds16(vsrc[i] + nk, &Vn[(i * 512 + w * 64) * 8]);
      }
    }
    __builtin_amdgcn_sched_barrier(0);

    // --- (C) S = K Q^T over this k-half (8 kf reads, 16 MFMA) ---
    f32x4 sacc[2][2];
#pragma unroll
    for (int rt = 0; rt < 2; ++rt)
#pragma unroll
      for (int n = 0; n < 2; ++n) sacc[rt][n] = (f32x4){0.f, 0.f, 0.f, 0.f};
    __builtin_amdgcn_s_setprio(1);
#pragma unroll
    for (int n = 0; n < 2; ++n) {
      const int kr = kh * 32 + n * 16 + lr;
#pragma unroll
      for (int kk = 0; kk < 4; ++kk) {
        const int cp = (kk * 4 + lg) ^ (lr & 7);
        bf16x8 kf = *(const bf16x8*)(Kb + (kr << 8) + (cp << 4));
        sacc[0][n] = __builtin_amdgcn_mfma_f32_16x16x32_bf16(kf, qf[0][kk], sacc[0][n], 0, 0, 0);
        sacc[1][n] = __builtin_amdgcn_mfma_f32_16x16x32_bf16(kf, qf[1][kk], sacc[1][n], 0, 0, 0);
      }
    }
    __builtin_amdgcn_s_setprio(0);

    // --- (D)+(E) per-rt lane-local softmax (defer-max) + P -> LDS ---
#pragma unroll
    for (int rt = 0; rt < 2; ++rt) {
      float sv[2][4];
      float tm = -1e30f;
#pragma unroll
      for (int n = 0; n < 2; ++n)
#pragma unroll
        for (int r = 0; r < 4; ++r) {
          float x = fmaf(sacc[rt][n][r], QK_SCALE, mk[rt][n][r]);
          sv[n][r] = x;
          tm = fmaxf(tm, x);
        }
      tm = fmaxf(tm, __shfl_xor(tm, 16));
      tm = fmaxf(tm, __shfl_xor(tm, 32));
      if (!__all(tm <= mrw[rt] + 8.f)) {
        const float mn = fmaxf(mrw[rt], tm);
        const float corr = __expf(mrw[rt] - mn);
        mrw[rt] = mn;
        lrw[rt] *= corr;
        float cb[4];
#pragma unroll
        for (int r = 0; r < 4; ++r) cb[r] = __shfl(corr, lg * 4 + r);
#pragma unroll
        for (int n = 0; n < 8; ++n)
#pragma unroll
          for (int r = 0; r < 4; ++r) acco[rt][n][r] *= cb[r];
      }
      float ls = 0.f;
#pragma unroll
      for (int n = 0; n < 2; ++n)
#pragma unroll
        for (int r = 0; r < 4; ++r) {
          float p = __expf(sv[n][r] - mrw[rt]);
          sv[n][r] = p;
          ls += p;
        }
      ls += __shfl_xor(ls, 16);
      ls += __shfl_xor(ls, 32);
      lrw[rt] += ls;
      // P write: row rt*16+lr, byte (n*32+lg*8+rp*4) ^ ((lr&3)<<4)
#pragma unroll
      for (int n = 0; n < 2; ++n)
#pragma unroll
        for (int rp = 0; rp < 2; ++rp) {
          bf16x2 pk = { (__bf16)sv[n][2 * rp], (__bf16)sv[n][2 * rp + 1] };
          const int pbyte = (n * 32 + lg * 8 + rp * 4) ^ ((lr & 3) << 4);
          *(bf16x2*)(Pw + (rt * 16 + lr) * 64 + pbyte) = pk;
        }
    }
    __asm__ volatile("s_waitcnt lgkmcnt(0)" ::: "memory");
    __builtin_amdgcn_sched_barrier(0);

    // --- (F) O += P V over this k-half (2 pa + 8 vf reads, 16 MFMA) ---
    __builtin_amdgcn_s_setprio(1);
    bf16x8 pa0 = *(const bf16x8*)(
        Pw + (lr) * 64 + ((lg ^ (lr & 3)) << 4));
    bf16x8 pa1 = *(const bf16x8*)(
        Pw + (16 + lr) * 64 + ((lg ^ (lr & 3)) << 4));
#pragma unroll
    for (int n = 0; n < 8; ++n) {
      const int vd = n * 16 + lr;
      const int cp = (kh * 4 + lg) ^ (lr & 7);
      bf16x8 vf = *(const bf16x8*)(Vb + (vd << 7) + (cp << 4));
      acco[0][n] = __builtin_amdgcn_mfma_f32_16x16x32_bf16(pa0, vf, acco[0][n], 0, 0, 0);
      acco[1][n] = __builtin_amdgcn_mfma_f32_16x16x32_bf16(pa1, vf, acco[1][n], 0, 0, 0);
    }
    __builtin_amdgcn_s_setprio(0);

    // --- (G) publish next buffer / protect current ---
    __syncthreads();
  }

  // ---- epilogue: exact two-way merge of the k-halves, then write out ----
  // Upper waves (kh=1) publish N (acco), m, l through the dead K/V LDS.
  f32x4* const fb  = (f32x4*)sm;              // [16][256] f32x4 = 64 KB
  float* const mlm = (float*)(sm + 65536);    // [4][2][64]
  float* const mll = mlm + 512;               // [4][2][64]
  if (kh == 1) {
#pragma unroll
    for (int rt = 0; rt < 2; ++rt) {
#pragma unroll
      for (int n = 0; n < 8; ++n)
        fb[(rt * 8 + n) * 256 + qw * 64 + lane] = acco[rt][n];
      mlm[(qw * 2 + rt) * 64 + lane] = mrw[rt];
      mll[(qw * 2 + rt) * 64 + lane] = lrw[rt];
    }
  }
  __syncthreads();
  if (kh == 0) {
#pragma unroll
    for (int rt = 0; rt < 2; ++rt) {
      const float m1 = mlm[(qw * 2 + rt) * 64 + lane];
      const float l1 = mll[(qw * 2 + rt) * 64 + lane];
      const float M  = fmaxf(mrw[rt], m1);
      const float a0 = __expf(mrw[rt] - M);
      const float a1 = __expf(m1 - M);
      const float lc = lrw[rt] * a0 + l1 * a1;
      float a0r[4], a1r[4], invr[4];
#pragma unroll
      for (int r = 0; r < 4; ++r) {
        a0r[r] = __shfl(a0, lg * 4 + r);
        a1r[r] = __shfl(a1, lg * 4 + r);
        invr[r] = 1.0f / __shfl(lc, lg * 4 + r);
      }
#pragma unroll
      for (int n = 0; n < 8; ++n) {
        f32x4 pn = fb[(rt * 8 + n) * 256 + qw * 64 + lane];
#pragma unroll
        for (int r = 0; r < 4; ++r) {
          const int srow = qb + rt * 16 + lg * 4 + r;
          Out[((size_t)b * SEQ + srow) * HDIM + h * HDSZ + n * 16 + lr] =
              (__bf16)((acco[rt][n][r] * a0r[r] + pn[r] * a1r[r]) * invr[r]);
        }
      }
    }
  }
}

// ---------------- launcher ----------------
extern "C" void kernel_launch(void* const* d_in, const int* in_sizes, int n_in,
                              void* d_out, int out_size, void* d_ws, size_t ws_size,
                              hipStream_t stream) {
  const float* x    = (const float*)d_in[0];
  const float* mask = (const float*)d_in[1];
  const float* wq   = (const float*)d_in[2];
  const float* wk   = (const float*)d_in[3];
  const float* wv   = (const float*)d_in[4];
  const float* wo   = (const float*)d_in[5];

  constexpr long XN = 4096L * 2048;  // 8388608
  constexpr long WN = 2048L * 2048;  // 4194304

  __bf16* xbf = (__bf16*)d_ws;
  __bf16* wqb = xbf + XN;            // wq;wk;wv;wo contiguous (cast6)
  __bf16* wob = wqb + 3 * WN;
  __bf16* qw  = wqb + 4 * WN;        // Q [b,h,s,d]
  __bf16* kw  = qw + XN;             // K [b,h,s,d]
  __bf16* vtw = kw + XN;             // V^T [b,h,d,s]
  __bf16* aw  = vtw + XN;            // attention output [4096][2048]

  cast6_f32_bf16<<<dim3(256, 6), 256, 0, stream>>>(x, wq, wk, wv, wo, xbf,
                                                   (int)(WN / 4));

  gemm_qkv<<<dim3(48, 32), 256, 0, stream>>>(xbf, wqb, qw);

  attn_fused<<<dim3(16, 32), 512, 0, stream>>>(qw, kw, vtw, mask, aw);

  gemm_bt_f32<<<dim3(16, 32), 256, 0, stream>>>(aw, wob, (float*)d_out,
                                                4096, 2048, 2048);
}

// Round 17
// 277.540 us; speedup vs baseline: 2.2755x; 2.2755x over previous
//
#include <hip/hip_runtime.h>
#include <stdint.h>

// Problem constants
constexpr int SEQ   = 2048;
constexpr int NHEAD = 16;
constexpr int HDSZ  = 128;   // head dim
constexpr int HDIM  = 2048;  // model dim
constexpr float QK_SCALE = 0.08838834764831845f; // 1/sqrt(128)

typedef __attribute__((ext_vector_type(8))) __bf16 bf16x8;
typedef __attribute__((ext_vector_type(4))) __bf16 bf16x4;
typedef __attribute__((ext_vector_type(2))) __bf16 bf16x2;
typedef __attribute__((ext_vector_type(4))) float  f32x4;

__device__ __forceinline__ void gl_lds16(const void* gptr, void* lptr) {
  // async global->LDS, 16B/lane; LDS dst is wave-uniform base + lane*16
  __builtin_amdgcn_global_load_lds(
      (const __attribute__((address_space(1))) unsigned int*)gptr,
      (__attribute__((address_space(3))) unsigned int*)lptr, 16, 0, 0);
}

// ---------------- merged fp32 -> bf16 cast (x + 4 weights, one launch) -------
__global__ __launch_bounds__(256) void cast6_f32_bf16(
    const float* __restrict__ x,  const float* __restrict__ w0,
    const float* __restrict__ w1, const float* __restrict__ w2,
    const float* __restrict__ w3, __bf16* __restrict__ out, int n4) {
  const int y = blockIdx.y;
  const float* src =
      (y == 0) ? x : (y == 1) ? x + (size_t)n4 * 4
      : (y == 2) ? w0 : (y == 3) ? w1 : (y == 4) ? w2 : w3;
  __bf16* dst = out + (size_t)y * (size_t)n4 * 4;
  int i = blockIdx.x * blockDim.x + threadIdx.x;
  int stride = gridDim.x * blockDim.x;
  for (; i < n4; i += stride) {
    float4 v = ((const float4*)src)[i];
    bf16x4 o = { (__bf16)v.x, (__bf16)v.y, (__bf16)v.z, (__bf16)v.w };
    ((bf16x4*)dst)[i] = o;
  }
}

// ---------------- merged QKV GEMM (BK=64, T2 swizzle, static dbuf) -----------
// (R13: 2-D XCD tiling, conflict-free swizzle, static double buffer)
__global__ __launch_bounds__(256) void gemm_qkv(
    const __bf16* __restrict__ A, const __bf16* __restrict__ W,
    __bf16* __restrict__ qkv) {
  constexpr long XN = 4096L * 2048;
  constexpr int K = 2048;
  __shared__ __align__(16) char smem[4 * 16384];  // As0|Bs0|As1|Bs1
  __bf16* const As0 = (__bf16*)(smem);
  __bf16* const Bs0 = (__bf16*)(smem + 16384);
  __bf16* const As1 = (__bf16*)(smem + 32768);
  __bf16* const Bs1 = (__bf16*)(smem + 49152);
  __bf16* const Ts  = (__bf16*)(smem);            // [64][136] epilogue reuse

  const int tid  = threadIdx.x;
  const int lane = tid & 63;
  const int w    = tid >> 6;
  const int lg   = lane >> 4, lr = lane & 15;
  const int wr   = w >> 1, wc = w & 1;
  const int flat = blockIdx.y * 48 + blockIdx.x;
  const int x8 = flat & 7, k = flat >> 3;        // k in 0..191
  const int xm = x8 & 3, xn = x8 >> 2;
  const int mtile = xm * 8 + (k & 7);
  const int ntile = xn * 24 + (k >> 3);
  const long mbase = (long)mtile * 128;
  const long nbase = (long)ntile * 128;

  f32x4 acc[4][4];
#pragma unroll
  for (int i = 0; i < 4; ++i)
#pragma unroll
    for (int j = 0; j < 4; ++j) acc[i][j] = (f32x4){0.f, 0.f, 0.f, 0.f};

  const __bf16* asrc[4];
  const __bf16* wsrc[4];
#pragma unroll
  for (int i = 0; i < 4; ++i) {
    const int row = w * 32 + i * 8 + (lane >> 3);
    const int cs  = ((lane & 7) ^ (row & 7)) * 8;
    asrc[i] = A + (mbase + row) * (long)K + cs;
    wsrc[i] = W + (nbase + row) * (long)K + cs;
  }

  auto stageto = [&](__bf16* As, __bf16* Bs, int ko) {
#pragma unroll
    for (int i = 0; i < 4; ++i) {
      gl_lds16(asrc[i] + ko, &As[(w * 32 + i * 8) * 64]);
      gl_lds16(wsrc[i] + ko, &Bs[(w * 32 + i * 8) * 64]);
    }
  };
  auto computeb = [&](const __bf16* As, const __bf16* Bs) {
#pragma unroll
    for (int kk = 0; kk < 2; ++kk) {
      const int cp = ((kk * 4 + lg) ^ (lr & 7)) << 4;
      bf16x8 af[4], bfv[4];
#pragma unroll
      for (int mm = 0; mm < 4; ++mm)
        af[mm] = *(const bf16x8*)(
            (const char*)As + (wr * 64 + mm * 16 + lr) * 128 + cp);
#pragma unroll
      for (int nn = 0; nn < 4; ++nn)
        bfv[nn] = *(const bf16x8*)(
            (const char*)Bs + (wc * 64 + nn * 16 + lr) * 128 + cp);
      __builtin_amdgcn_s_setprio(1);
#pragma unroll
      for (int nn = 0; nn < 4; ++nn)
#pragma unroll
        for (int mm = 0; mm < 4; ++mm)
          acc[mm][nn] = __builtin_amdgcn_mfma_f32_16x16x32_bf16(
              af[mm], bfv[nn], acc[mm][nn], 0, 0, 0);
      __builtin_amdgcn_s_setprio(0);
    }
  };

  stageto(As0, Bs0, 0);
  __syncthreads();

  int ko = 64;
  for (int tp = 0; tp < 15; ++tp) {
    stageto(As1, Bs1, ko);
    __builtin_amdgcn_sched_barrier(0);
    computeb(As0, Bs0);
    __syncthreads();
    stageto(As0, Bs0, ko + 64);
    __builtin_amdgcn_sched_barrier(0);
    computeb(As1, Bs1);
    __syncthreads();
    ko += 128;
  }
  stageto(As1, Bs1, ko);
  __builtin_amdgcn_sched_barrier(0);
  computeb(As0, Bs0);
  __syncthreads();
  computeb(As1, Bs1);
  __syncthreads();  // before Ts reuse

  const int  mat = ntile >> 4;                // 0=Q, 1=K, 2=V
  const long nb2 = nbase - (long)mat * 2048;
  const long b   = mbase >> 11, s0 = mbase & 2047;
  const long h   = nb2 >> 7;

  if (mat < 2) {
    __bf16* out = qkv + (size_t)mat * XN;
#pragma unroll
    for (int dh = 0; dh < 2; ++dh) {
      if (wr == dh) {
#pragma unroll
        for (int mm = 0; mm < 4; ++mm)
#pragma unroll
          for (int nn = 0; nn < 4; ++nn) {
            const int d = wc * 64 + nn * 16 + lr;
#pragma unroll
            for (int r = 0; r < 4; ++r)
              Ts[(mm * 16 + lg * 4 + r) * 136 + d] = (__bf16)acc[mm][nn][r];
          }
      }
      __syncthreads();
#pragma unroll
      for (int it = 0; it < 4; ++it) {
        const int idx = it * 256 + tid;
        const int row = idx >> 4, c = idx & 15;
        bf16x8 v = *(const bf16x8*)&Ts[row * 136 + c * 8];
        *(bf16x8*)&out[((b * NHEAD + h) * SEQ + s0 + dh * 64 + row) * HDSZ +
                       c * 8] = v;
      }
      __syncthreads();
    }
  } else {
    __bf16* out = qkv + 2 * XN;
#pragma unroll
    for (int dh = 0; dh < 2; ++dh) {
      if (wc == dh) {
#pragma unroll
        for (int mm = 0; mm < 4; ++mm)
#pragma unroll
          for (int nn = 0; nn < 4; ++nn) {
            const int dd = nn * 16 + lr;
            bf16x4 pk = { (__bf16)acc[mm][nn][0], (__bf16)acc[mm][nn][1],
                          (__bf16)acc[mm][nn][2], (__bf16)acc[mm][nn][3] };
            *(bf16x4*)&Ts[dd * 136 + wr * 64 + mm * 16 + lg * 4] = pk;
          }
      }
      __syncthreads();
#pragma unroll
      for (int it = 0; it < 4; ++it) {
        const int idx = it * 256 + tid;
        const int dd = idx >> 4, c = idx & 15;
        bf16x8 v = *(const bf16x8*)&Ts[dd * 136 + c * 8];
        *(bf16x8*)&out[((b * NHEAD + h) * HDSZ + dh * 64 + dd) * SEQ +
                       s0 + c * 8] = v;
      }
      __syncthreads();
    }
  }
}

// ---------------- O-projection GEMM (fp32 out; BK=64, T2, static dbuf) -------
__global__ __launch_bounds__(256) void gemm_bt_f32(
    const __bf16* __restrict__ A, const __bf16* __restrict__ B,
    float* __restrict__ C, int M, int N, int K) {
  __shared__ __align__(16) char smem[4 * 16384];
  __bf16* const As0 = (__bf16*)(smem);
  __bf16* const Bs0 = (__bf16*)(smem + 16384);
  __bf16* const As1 = (__bf16*)(smem + 32768);
  __bf16* const Bs1 = (__bf16*)(smem + 49152);

  const int tid  = threadIdx.x;
  const int lane = tid & 63;
  const int w    = tid >> 6;
  const int lg   = lane >> 4, lr = lane & 15;
  const int wr   = w >> 1, wc = w & 1;
  const int flat = blockIdx.y * 16 + blockIdx.x;
  const int x8 = flat & 7, k = flat >> 3;
  const int xm = x8 & 3, xn = x8 >> 2;
  const long mbase = (long)(xm * 8 + (k & 7)) * 128;
  const long nbase = (long)(xn * 8 + (k >> 3)) * 128;

  f32x4 acc[4][4];
#pragma unroll
  for (int i = 0; i < 4; ++i)
#pragma unroll
    for (int j = 0; j < 4; ++j) acc[i][j] = (f32x4){0.f, 0.f, 0.f, 0.f};

  const __bf16* asrc[4];
  const __bf16* bsrc[4];
#pragma unroll
  for (int i = 0; i < 4; ++i) {
    const int row = w * 32 + i * 8 + (lane >> 3);
    const int cs  = ((lane & 7) ^ (row & 7)) * 8;
    asrc[i] = A + (mbase + row) * (long)K + cs;
    bsrc[i] = B + (nbase + row) * (long)K + cs;
  }

  auto stageto = [&](__bf16* As, __bf16* Bs, int ko) {
#pragma unroll
    for (int i = 0; i < 4; ++i) {
      gl_lds16(asrc[i] + ko, &As[(w * 32 + i * 8) * 64]);
      gl_lds16(bsrc[i] + ko, &Bs[(w * 32 + i * 8) * 64]);
    }
  };
  auto computeb = [&](const __bf16* As, const __bf16* Bs) {
#pragma unroll
    for (int kk = 0; kk < 2; ++kk) {
      const int cp = ((kk * 4 + lg) ^ (lr & 7)) << 4;
      bf16x8 af[4], bfv[4];
#pragma unroll
      for (int mm = 0; mm < 4; ++mm)
        af[mm] = *(const bf16x8*)(
            (const char*)As + (wr * 64 + mm * 16 + lr) * 128 + cp);
#pragma unroll
      for (int nn = 0; nn < 4; ++nn)
        bfv[nn] = *(const bf16x8*)(
            (const char*)Bs + (wc * 64 + nn * 16 + lr) * 128 + cp);
      __builtin_amdgcn_s_setprio(1);
#pragma unroll
      for (int nn = 0; nn < 4; ++nn)
#pragma unroll
        for (int mm = 0; mm < 4; ++mm)
          acc[mm][nn] = __builtin_amdgcn_mfma_f32_16x16x32_bf16(
              af[mm], bfv[nn], acc[mm][nn], 0, 0, 0);
      __builtin_amdgcn_s_setprio(0);
    }
  };

  stageto(As0, Bs0, 0);
  __syncthreads();

  int ko = 64;
  for (int tp = 0; tp < 15; ++tp) {
    stageto(As1, Bs1, ko);
    __builtin_amdgcn_sched_barrier(0);
    computeb(As0, Bs0);
    __syncthreads();
    stageto(As0, Bs0, ko + 64);
    __builtin_amdgcn_sched_barrier(0);
    computeb(As1, Bs1);
    __syncthreads();
    ko += 128;
  }
  stageto(As1, Bs1, ko);
  __builtin_amdgcn_sched_barrier(0);
  computeb(As0, Bs0);
  __syncthreads();
  computeb(As1, Bs1);

#pragma unroll
  for (int mm = 0; mm < 4; ++mm)
#pragma unroll
    for (int nn = 0; nn < 4; ++nn) {
      const long n = nbase + wc * 64 + nn * 16 + lr;
#pragma unroll
      for (int r = 0; r < 4; ++r) {
        const long m = mbase + wr * 64 + mm * 16 + lg * 4 + r;
        C[m * (long)N + n] = acc[mm][nn][r];
      }
    }
}

// ---------------- fused flash attention v6.2 (R15 version, reverted) ---------
// QBLK=128, KVBLK=64, 8 waves (512 threads); wave owns 16 q-rows; 80KB LDS
// -> 2 blocks/CU. SWAPPED QK^T lane-local softmax (2 shfl_xor).
// T13 defer-max: when __all(tile_max <= running_max + 8), skip the rescale.
__global__ __launch_bounds__(512, 4) void attn_fused(
    const __bf16* __restrict__ Q, const __bf16* __restrict__ K,
    const __bf16* __restrict__ Vt, const float* __restrict__ mask,
    __bf16* __restrict__ Out) {
  __shared__ __bf16 Ks[2 * 64 * 128];   // [buf][krow][d], swizzled chunks
  __shared__ __bf16 Vs[2 * 128 * 64];   // [buf][d][kcol], swizzled chunks
  __shared__ __bf16 Ps[128 * 64];       // [qrow][k], byte = 2k ^ ((q&7)<<4)

  const int tid  = threadIdx.x;
  const int lane = tid & 63;
  const int w    = tid >> 6;            // 0..7
  const int lg   = lane >> 4, lr = lane & 15;
  const int flat = blockIdx.y * 16 + blockIdx.x;
  const int swz  = (flat & 7) * 64 + (flat >> 3);
  const int bh   = swz >> 4;
  const int b    = bh >> 4, h = bh & 15;
  const int q0   = (swz & 15) * 128;

  const __bf16* Qh = Q  + (size_t)bh * SEQ * HDSZ;
  const __bf16* Kh = K  + (size_t)bh * SEQ * HDSZ;
  const __bf16* Vh = Vt + (size_t)bh * HDSZ * SEQ;  // [d][s]
  const float*  Mb = mask + (size_t)b * SEQ * SEQ;

  // Q fragments (B-operand: col=lr -> q-row, k=lg*8+i -> d)
  bf16x8 qf[4];
#pragma unroll
  for (int kk = 0; kk < 4; ++kk)
    qf[kk] = *(const bf16x8*)(
        Qh + (size_t)(q0 + w * 16 + lr) * HDSZ + kk * 32 + lg * 8);

  // staging sources (pre-swizzled global addr, linear LDS dest)
  const __bf16* ksrc[2];
  const __bf16* vsrc[2];
#pragma unroll
  for (int i = 0; i < 2; ++i) {
    const int ch = i * 512 + tid;
    const int krow = ch >> 4, kc = ch & 15;
    ksrc[i] = Kh + (size_t)krow * HDSZ + (((kc & 8) | ((kc ^ krow) & 7)) * 8);
    const int vrow = ch >> 3, vc = ch & 7;
    vsrc[i] = Vh + (size_t)vrow * SEQ + (((vc ^ vrow) & 7) * 8);
  }

  float mrw = -1e30f, lrw = 0.f;     // scalar per lane (q = lr)
  f32x4 acco[8];
#pragma unroll
  for (int n = 0; n < 8; ++n) acco[n] = (f32x4){0.f, 0.f, 0.f, 0.f};

  // prologue: stage tile 0 into buffer 0
#pragma unroll
  for (int i = 0; i < 2; ++i) {
    gl_lds16(ksrc[i], &Ks[(i * 512 + w * 64) * 8]);
    gl_lds16(vsrc[i], &Vs[(i * 512 + w * 64) * 8]);
  }
  __syncthreads();

  constexpr int NT = SEQ / 64;
  for (int t = 0; t < NT; ++t) {
    const int cur = t & 1;
    const int kt = t * 64;
    const char* Kb = (const char*)(Ks + cur * (64 * 128));
    const char* Vb = (const char*)(Vs + cur * (128 * 64));

    // --- (A) mask prefetch (float4, k = n*16 + lg*4 + 0..3) ---
    f32x4 mk[4];
#pragma unroll
    for (int n = 0; n < 4; ++n)
      mk[n] = *(const f32x4*)(
          Mb + (size_t)(q0 + w * 16 + lr) * SEQ + kt + n * 16 + lg * 4);
    __builtin_amdgcn_sched_barrier(0);

    // --- (B) STAGE tile t+1 into buf^1 (drained at end barrier) ---
    if (t + 1 < NT) {
      const int nk = kt + 64;
      __bf16* Kn = Ks + (cur ^ 1) * (64 * 128);
      __bf16* Vn = Vs + (cur ^ 1) * (128 * 64);
#pragma unroll
      for (int i = 0; i < 2; ++i) {
        gl_lds16(ksrc[i] + (size_t)nk * HDSZ, &Kn[(i * 512 + w * 64) * 8]);
        gl_lds16(vsrc[i] + nk, &Vn[(i * 512 + w * 64) * 8]);
      }
    }
    __builtin_amdgcn_sched_barrier(0);

    // --- (C) S = K Q^T (SWAPPED: lane gets q=lr, k=n*16+lg*4+r) ---
    f32x4 sacc[4];
#pragma unroll
    for (int n = 0; n < 4; ++n) sacc[n] = (f32x4){0.f, 0.f, 0.f, 0.f};
    __builtin_amdgcn_s_setprio(1);
#pragma unroll
    for (int n = 0; n < 4; ++n)
#pragma unroll
      for (int kk = 0; kk < 4; ++kk) {
        const int cp = (kk * 4 + lg) ^ (lr & 7);  // swizzled 16B chunk
        bf16x8 kf = *(const bf16x8*)(Kb + ((n * 16 + lr) << 8) + (cp << 4));
        sacc[n] = __builtin_amdgcn_mfma_f32_16x16x32_bf16(kf, qf[kk], sacc[n], 0, 0, 0);
      }
    __builtin_amdgcn_s_setprio(0);

    // --- (D) lane-local online softmax with T13 defer-max ---
    float sv[4][4];
    float tm = -1e30f;
#pragma unroll
    for (int n = 0; n < 4; ++n)
#pragma unroll
      for (int r = 0; r < 4; ++r) {
        float x = fmaf(sacc[n][r], QK_SCALE, mk[n][r]);
        sv[n][r] = x;
        tm = fmaxf(tm, x);
      }
    tm = fmaxf(tm, __shfl_xor(tm, 16));
    tm = fmaxf(tm, __shfl_xor(tm, 32));
    if (!__all(tm <= mrw + 8.f)) {
      const float mn = fmaxf(mrw, tm);
      const float corr = __expf(mrw - mn);
      mrw = mn;
      lrw *= corr;
      float cb[4];
#pragma unroll
      for (int r = 0; r < 4; ++r) cb[r] = __shfl(corr, lg * 4 + r);
#pragma unroll
      for (int n = 0; n < 8; ++n)
#pragma unroll
        for (int r = 0; r < 4; ++r) acco[n][r] *= cb[r];
    }
    float ls = 0.f;
#pragma unroll
    for (int n = 0; n < 4; ++n)
#pragma unroll
      for (int r = 0; r < 4; ++r) {
        float p = __expf(sv[n][r] - mrw);
        sv[n][r] = p;
        ls += p;
      }
    ls += __shfl_xor(ls, 16);
    ls += __shfl_xor(ls, 32);
    lrw += ls;

    // --- (E) P -> LDS, packed b32 (k pairs are r-adjacent) ---
#pragma unroll
    for (int n = 0; n < 4; ++n)
#pragma unroll
      for (int rp = 0; rp < 2; ++rp) {
        bf16x2 pk = { (__bf16)sv[n][2 * rp], (__bf16)sv[n][2 * rp + 1] };
        const int pbyte = (n * 32 + lg * 8 + rp * 4) ^ ((lr & 7) << 4);
        *(bf16x2*)((char*)Ps + (w * 16 + lr) * 128 + pbyte) = pk;
      }
    __asm__ volatile("s_waitcnt lgkmcnt(0)" ::: "memory");
    __builtin_amdgcn_sched_barrier(0);

    // --- (F) O += P V ---
    __builtin_amdgcn_s_setprio(1);
#pragma unroll
    for (int kk = 0; kk < 2; ++kk) {
      const int pcp = (kk * 4 + lg) ^ (lr & 7);
      bf16x8 pa = *(const bf16x8*)(
          (const char*)Ps + (w * 16 + lr) * 128 + (pcp << 4));
#pragma unroll
      for (int n = 0; n < 8; ++n) {
        const int cp = (kk * 4 + lg) ^ (lr & 7);
        bf16x8 vf = *(const bf16x8*)(Vb + ((n * 16 + lr) << 7) + (cp << 4));
        acco[n] = __builtin_amdgcn_mfma_f32_16x16x32_bf16(pa, vf, acco[n], 0, 0, 0);
      }
    }
    __builtin_amdgcn_s_setprio(0);

    // --- (G) publish next buffer / protect current ---
    __syncthreads();
  }

  // --- epilogue: normalize, write attn out as [b, s, h*128+d] bf16 ---
  float lb[4];
#pragma unroll
  for (int r = 0; r < 4; ++r) lb[r] = __shfl(lrw, lg * 4 + r);
#pragma unroll
  for (int r = 0; r < 4; ++r) {
    const float inv = 1.0f / lb[r];
    const int srow = q0 + w * 16 + lg * 4 + r;
    const size_t base = ((size_t)b * SEQ + srow) * HDIM + h * HDSZ;
#pragma unroll
    for (int n = 0; n < 8; ++n)
      Out[base + n * 16 + lr] = (__bf16)(acco[n][r] * inv);
  }
}

// ---------------- launcher ----------------
extern "C" void kernel_launch(void* const* d_in, const int* in_sizes, int n_in,
                              void* d_out, int out_size, void* d_ws, size_t ws_size,
                              hipStream_t stream) {
  const float* x    = (const float*)d_in[0];
  const float* mask = (const float*)d_in[1];
  const float* wq   = (const float*)d_in[2];
  const float* wk   = (const float*)d_in[3];
  const float* wv   = (const float*)d_in[4];
  const float* wo   = (const float*)d_in[5];

  constexpr long XN = 4096L * 2048;  // 8388608
  constexpr long WN = 2048L * 2048;  // 4194304

  __bf16* xbf = (__bf16*)d_ws;
  __bf16* wqb = xbf + XN;            // wq;wk;wv;wo contiguous (cast6)
  __bf16* wob = wqb + 3 * WN;
  __bf16* qw  = wqb + 4 * WN;        // Q [b,h,s,d]
  __bf16* kw  = qw + XN;             // K [b,h,s,d]
  __bf16* vtw = kw + XN;             // V^T [b,h,d,s]
  __bf16* aw  = vtw + XN;            // attention output [4096][2048]

  cast6_f32_bf16<<<dim3(256, 6), 256, 0, stream>>>(x, wq, wk, wv, wo, xbf,
                                                   (int)(WN / 4));

  gemm_qkv<<<dim3(48, 32), 256, 0, stream>>>(xbf, wqb, qw);

  attn_fused<<<dim3(16, 32), 512, 0, stream>>>(qw, kw, vtw, mask, aw);

  gemm_bt_f32<<<dim3(16, 32), 256, 0, stream>>>(aw, wob, (float*)d_out,
                                                4096, 2048, 2048);
}